// Round 8
// baseline (166.727 us; speedup 1.0000x reference)
//
#include <hip/hip_runtime.h>
#include <hip/hip_cooperative_groups.h>
#include <math.h>

namespace cg = cooperative_groups;

#define PUPIL 256
#define N_BINS 8
#define BATCH 16

__constant__ int PHASE_NS_C[N_BINS] = {1024, 988, 952, 918, 886, 856, 828, 802};

typedef short bf16x8 __attribute__((ext_vector_type(8)));
typedef short bf16x4 __attribute__((ext_vector_type(4)));
typedef float f32x4  __attribute__((ext_vector_type(4)));
typedef int   i32x4  __attribute__((ext_vector_type(4)));

#define MFMA16(a, b, c) __builtin_amdgcn_mfma_f32_16x16x32_bf16((a), (b), (c), 0, 0, 0)

__device__ __forceinline__ short f2bf(float f) {   // RNE float->bf16
  unsigned u = __float_as_uint(f);
  u += 0x7FFFu + ((u >> 16) & 1u);
  return (short)(u >> 16);
}
__device__ __forceinline__ bf16x8 neg8(bf16x8 v) {
  i32x4 t = __builtin_bit_cast(i32x4, v);
  t ^= (int)0x80008000;
  return __builtin_bit_cast(bf16x8, t);
}

// ---------------------------------------------------------------------------
// PSF[u,v] = | sum_{y,x} P[y,x] W[y,u] W[x,v] |^2 ; W[n,k]=e^{-2pi i (k-32) n/N}
// R8: ONE cooperative kernel (R4-R7 lesson: structure barely moves the
// ~45us non-fill budget; remove ALL inter-kernel nodes at once).
// 256 blocks x 512 thr; each block = 2 independent 256-thr halves in lockstep
// (2 waves/SIMD). Phases separated by grid.sync():
//  A: stage1 G^T[kv][y] = sum_x W[kv][x] P[y][x], 1024 units (R7 body; W via
//     1 sincos + 7 rotation steps per 8-chunk; (b==0,yc==0) persists W_t).
//  B: stage2 H^T[kv][ku] = sum_y G^T[kv][y] W[ku][y], 512 units (R6 body),
//     writes psf_raw + per-(bb,uc) partial sums. No atomics.
//  C: combine: scale sed/S, sum bins -> out.
// MFMA 16x16x32 bf16 (verified R4-R7): A[m=lane&15][k=quad*8+j] 16B contig,
// B-frag = B^T row, D: col(lane&15)=N-dim, row(quad*4+reg)=M-dim.
// ---------------------------------------------------------------------------

__global__ __launch_bounds__(512, 2) void mega(
    const float* __restrict__ opd, const float* __restrict__ obsc,
    const float* __restrict__ lambdas, const float* __restrict__ sed,
    short* __restrict__ Wr_t, short* __restrict__ Wi_t,
    short* __restrict__ Gr_t, short* __restrict__ Gi_t,
    float* __restrict__ psf_raw, float* __restrict__ sums,
    float* __restrict__ out)
{
  const int blk = blockIdx.x;          // 0..255
  const int tid = threadIdx.x;         // 0..511
  const int h    = tid >> 8;           // half 0/1
  const int htid = tid & 255;

  __shared__ short Pr[2][32 * 32], Pi[2][32 * 32];
  __shared__ float pvbuf[2][64 * 17];
  __shared__ float red[2][4];
  __shared__ float sc[N_BINS];

  const int wave = htid >> 6, lane = htid & 63;
  const int lr = lane & 15, lq = lane >> 4;

  // ---------------- phase A: stage1, 2 units per half ----------------
  for (int it = 0; it < 2; ++it) {
    const int unit = (blk * 2 + h) * 2 + it;        // 0..1023
    const int yc = unit & 7, bin = (unit >> 3) & 7, b = unit >> 6;
    const int yb = yc * 32;
    const int bb = b * N_BINS + bin;
    const float w0 = 6.283185307179586f / lambdas[bin];
    const float npiN = -6.283185307179586f / (float)PHASE_NS_C[bin];
    const bool storeW = (yc == 0) && (b == 0);

    const int kvm = wave * 16 + lr - 32;
    float stepS, stepC;
    __sincosf((float)kvm * npiN, &stepS, &stepC);   // e^{-2pi i kvm/N}

    f32x4 aR[2], aI[2];
    aR[0] = (f32x4)0.0f; aR[1] = (f32x4)0.0f;
    aI[0] = (f32x4)0.0f; aI[1] = (f32x4)0.0f;

    const int gy = htid >> 3;           // 0..31
    const int gx = (htid & 7) * 4;      // 0,4,..,28
    const float* orow = opd + ((size_t)b * PUPIL + yb + gy) * PUPIL;
    const float* brow = obsc + (size_t)(yb + gy) * PUPIL;

    for (int xc = 0; xc < 8; ++xc) {
      const int xb = xc * 32;
      const float4 od = *(const float4*)(orow + xb + gx);
      const float4 ob = *(const float4*)(brow + xb + gx);
      bf16x4 vr, vi;
      {
        float s, c;
        __sincosf(w0 * od.x, &s, &c); vr[0] = f2bf(c * ob.x); vi[0] = f2bf(s * ob.x);
        __sincosf(w0 * od.y, &s, &c); vr[1] = f2bf(c * ob.y); vi[1] = f2bf(s * ob.y);
        __sincosf(w0 * od.z, &s, &c); vr[2] = f2bf(c * ob.z); vi[2] = f2bf(s * ob.z);
        __sincosf(w0 * od.w, &s, &c); vr[3] = f2bf(c * ob.w); vi[3] = f2bf(s * ob.w);
      }
      // W A-frag: anchor sincos + 7 rotations (err ~7eps << bf16 4e-3)
      bf16x8 w_r, w_i;
      {
        const int x0 = xb + lq * 8;
        float ps, pc;
        __sincosf((float)(kvm * x0) * npiN, &ps, &pc);
        w_r[0] = f2bf(pc); w_i[0] = f2bf(ps);
        #pragma unroll
        for (int j = 1; j < 8; ++j) {
          const float nc = pc * stepC - ps * stepS;
          const float ns = pc * stepS + ps * stepC;
          w_r[j] = f2bf(nc); w_i[j] = f2bf(ns);
          pc = nc; ps = ns;
        }
      }
      const bf16x8 nw_i = neg8(w_i);
      if (storeW) {
        const int kv = wave * 16 + lr;
        *(bf16x8*)&Wr_t[((size_t)bin * 64 + kv) * 256 + xb + lq * 8] = w_r;
        *(bf16x8*)&Wi_t[((size_t)bin * 64 + kv) * 256 + xb + lq * 8] = w_i;
      }
      __syncthreads();                        // prior chunk's frag reads done
      *(bf16x4*)&Pr[h][gy * 32 + gx] = vr;
      *(bf16x4*)&Pi[h][gy * 32 + gx] = vi;
      __syncthreads();                        // P chunk visible

      for (int t = 0; t < 2; ++t) {
        const bf16x8 pr = *(const bf16x8*)&Pr[h][(t * 16 + lr) * 32 + lq * 8];
        const bf16x8 pi = *(const bf16x8*)&Pi[h][(t * 16 + lr) * 32 + lq * 8];
        aR[t] = MFMA16(w_r,  pr, aR[t]);
        aR[t] = MFMA16(nw_i, pi, aR[t]);
        aI[t] = MFMA16(w_r,  pi, aI[t]);
        aI[t] = MFMA16(w_i,  pr, aI[t]);
      }
    }

    #pragma unroll
    for (int t = 0; t < 2; ++t) {
      const int y = yb + t * 16 + lr;           // D col -> y
      #pragma unroll
      for (int r = 0; r < 4; ++r) {
        const int kvd = wave * 16 + lq * 4 + r; // D row -> kv
        const size_t o = ((size_t)bb * 64 + kvd) * 256 + y;
        Gr_t[o] = f2bf(aR[t][r]);
        Gi_t[o] = f2bf(aI[t][r]);
      }
    }
  }

  cg::this_grid().sync();

  // ---------------- phase B: stage2, 1 unit per half ----------------
  {
    const int unit = blk * 2 + h;               // 0..511
    const int uc = unit & 3, bin = (unit >> 2) & 7, b = unit >> 5;
    const int bb = b * N_BINS + bin;

    f32x4 hR = (f32x4)0.0f, hI = (f32x4)0.0f;

    const short* grb = Gr_t + ((size_t)bb * 64 + wave * 16 + lr) * 256 + lq * 8;
    const short* gib = Gi_t + ((size_t)bb * 64 + wave * 16 + lr) * 256 + lq * 8;
    const short* wrb = Wr_t + ((size_t)bin * 64 + uc * 16 + lr) * 256 + lq * 8;
    const short* wib = Wi_t + ((size_t)bin * 64 + uc * 16 + lr) * 256 + lq * 8;

    for (int yc2 = 0; yc2 < 8; ++yc2) {
      const int yb2 = yc2 * 32;
      const bf16x8 g_r  = *(const bf16x8*)(grb + yb2);
      const bf16x8 g_i  = *(const bf16x8*)(gib + yb2);
      const bf16x8 w_r  = *(const bf16x8*)(wrb + yb2);
      const bf16x8 w_i  = *(const bf16x8*)(wib + yb2);
      const bf16x8 ng_i = neg8(g_i);
      hR = MFMA16(g_r,  w_r, hR);
      hR = MFMA16(ng_i, w_i, hR);
      hI = MFMA16(g_r,  w_i, hI);
      hI = MFMA16(g_i,  w_r, hI);
    }

    float pv[4], lsum = 0.f;
    #pragma unroll
    for (int r = 0; r < 4; ++r) {
      pv[r] = hR[r] * hR[r] + hI[r] * hI[r];
      lsum += pv[r];
    }
    #pragma unroll
    for (int off = 32; off > 0; off >>= 1) lsum += __shfl_down(lsum, off);
    if (lane == 0) red[h][wave] = lsum;

    // transpose via LDS: D row(lq*4+r)=kv, col(lr)=ku_local
    #pragma unroll
    for (int r = 0; r < 4; ++r)
      pvbuf[h][(wave * 16 + lq * 4 + r) * 17 + lr] = pv[r];
    __syncthreads();

    if (htid == 0)
      sums[bb * 4 + uc] = red[h][0] + red[h][1] + red[h][2] + red[h][3];

    #pragma unroll
    for (int it = 0; it < 4; ++it) {
      const int i  = htid + it * 256;           // 0..1023
      const int ul = i >> 6;                    // 0..15
      const int v  = i & 63;
      psf_raw[(size_t)bb * 4096 + (uc * 16 + ul) * 64 + v] = pvbuf[h][v * 17 + ul];
    }
  }

  cg::this_grid().sync();

  // ---------------- phase C: combine ----------------
  {
    const int b = blk >> 4;
    if (tid < N_BINS) {
      const int bb = b * N_BINS + tid;
      const float S = sums[bb * 4] + sums[bb * 4 + 1] + sums[bb * 4 + 2] + sums[bb * 4 + 3];
      sc[tid] = sed[tid] / S;
    }
    __syncthreads();
    if (tid < 256) {
      const int px = (blk & 15) * 256 + tid;
      float acc = 0.f;
      #pragma unroll
      for (int bin = 0; bin < N_BINS; ++bin)
        acc += sc[bin] * psf_raw[(size_t)(b * N_BINS + bin) * 4096 + px];
      out[b * 4096 + px] = acc;
    }
  }
}

extern "C" void kernel_launch(void* const* d_in, const int* in_sizes, int n_in,
                              void* d_out, int out_size, void* d_ws, size_t ws_size,
                              hipStream_t stream) {
  const float* opd     = (const float*)d_in[0];
  const float* obsc    = (const float*)d_in[1];
  const float* lambdas = (const float*)d_in[2];
  const float* sed     = (const float*)d_in[3];
  float* out = (float*)d_out;

  // ws: Wr_t 256KB | Wi_t 256KB | Gr_t 4MB | Gi_t 4MB | psf_raw 2MB | sums 2KB
  short* Wr_t = (short*)d_ws;
  short* Wi_t = Wr_t + (size_t)N_BINS * 64 * 256;
  short* Gr_t = Wi_t + (size_t)N_BINS * 64 * 256;
  short* Gi_t = Gr_t + (size_t)BATCH * N_BINS * 64 * 256;
  float* psf_raw = (float*)(Gi_t + (size_t)BATCH * N_BINS * 64 * 256);
  float* sums    = psf_raw + (size_t)BATCH * N_BINS * 4096;

  void* args[] = {(void*)&opd, (void*)&obsc, (void*)&lambdas, (void*)&sed,
                  (void*)&Wr_t, (void*)&Wi_t, (void*)&Gr_t, (void*)&Gi_t,
                  (void*)&psf_raw, (void*)&sums, (void*)&out};
  hipLaunchCooperativeKernel((void*)mega, dim3(256), dim3(512), args, 0, stream);
}

// Round 9
// 102.141 us; speedup vs baseline: 1.6323x; 1.6323x over previous
//
#include <hip/hip_runtime.h>
#include <math.h>

#define PUPIL 256
#define N_BINS 8
#define BATCH 16

__constant__ int PHASE_NS_C[N_BINS] = {1024, 988, 952, 918, 886, 856, 828, 802};

typedef short bf16x8 __attribute__((ext_vector_type(8)));
typedef float f32x4  __attribute__((ext_vector_type(4)));
typedef int   i32x4  __attribute__((ext_vector_type(4)));

#define MFMA16(a, b, c) __builtin_amdgcn_mfma_f32_16x16x32_bf16((a), (b), (c), 0, 0, 0)

__device__ __forceinline__ short f2bf(float f) {   // RNE float->bf16
  unsigned u = __float_as_uint(f);
  u += 0x7FFFu + ((u >> 16) & 1u);
  return (short)(u >> 16);
}
__device__ __forceinline__ bf16x8 neg8(bf16x8 v) {
  i32x4 t = __builtin_bit_cast(i32x4, v);
  t ^= (int)0x80008000;
  return __builtin_bit_cast(bf16x8, t);
}

// ---------------------------------------------------------------------------
// PSF[u,v] = | sum_{y,x} P[y,x] W[y,u] W[x,v] |^2 ; W[n,k]=e^{-2pi i (k-32) n/N}
// R9: R8 showed our kernels are latency-bound (mega 91us, VALU 10%, occ 22%).
// Fix = remove stalls, not add waves:
//  stage1 is BARRIER-FREE & LDS-FREE: wave = 16-row y-slab, so the MFMA
//  B-frag (P[y=lane&15][x-octet]) is exactly the 8 pixels each lane sincos's
//  from global. A-frags = W rows from wprep table (L1/L2-hot). Each wave
//  covers all 64 kv (4 A-tiles). Zero redundant sincos (8.4M total).
//  stage2 = R6's barrier-free K-loop + manual register double-buffer.
// MFMA 16x16x32 bf16 (verified R4-R8): A[m=lane&15][k=quad*8+j] 16B contig,
// B-frag = B^T row, D: col(lane&15)=N-dim, row(quad*4+reg)=M-dim.
// ---------------------------------------------------------------------------

// W_t[bin][k=64][n=256] bf16
__global__ void wprep(short* __restrict__ Wr_t, short* __restrict__ Wi_t) {
  int idx = blockIdx.x * 256 + threadIdx.x;   // 131072
  int n   = idx & 255;
  int k   = (idx >> 8) & 63;
  int bin = idx >> 14;
  int N = PHASE_NS_C[bin];
  int m = ((k - 32) * n) % N;
  if (m < 0) m += N;
  float ang = -6.283185307179586f * (float)m / (float)N;
  float s, c;
  __sincosf(ang, &s, &c);
  Wr_t[idx] = f2bf(c);
  Wi_t[idx] = f2bf(s);
}

// stage1: grid (4 yquad of 64, 8 bin, 16 b) = 512 blocks, 256 thr.
// No LDS, no barriers. Per wave: y-slab = yb + wave*16 + lr; per chunk xc:
// sincos 8 px -> B-frag; 4 kv-tile A-frags from W_t; 16 MFMA.
__global__ __launch_bounds__(256, 2) void stage1(
    const float* __restrict__ opd, const float* __restrict__ obsc,
    const float* __restrict__ lambdas,
    const short* __restrict__ Wr_t, const short* __restrict__ Wi_t,
    short* __restrict__ Gr_t, short* __restrict__ Gi_t)
{
  const int tid = threadIdx.x;
  const int yb = blockIdx.x * 64, bin = blockIdx.y, b = blockIdx.z;
  const int bb = b * N_BINS + bin;
  const float w0 = 6.283185307179586f / lambdas[bin];

  const int wave = tid >> 6, lane = tid & 63;
  const int lr = lane & 15, lq = lane >> 4;

  const int y  = yb + wave * 16 + lr;     // this thread's pixel row
  const int x0 = lq * 8;                  // x-octet within 32-wide chunk

  const float* orow = opd + ((size_t)b * PUPIL + y) * PUPIL;
  const float* brow = obsc + (size_t)y * PUPIL;
  const short* wrb = Wr_t + ((size_t)bin * 64 + lr) * 256 + x0;  // + t*16*256 + xb
  const short* wib = Wi_t + ((size_t)bin * 64 + lr) * 256 + x0;

  f32x4 aR[4], aI[4];
  #pragma unroll
  for (int t = 0; t < 4; ++t) { aR[t] = (f32x4)0.0f; aI[t] = (f32x4)0.0f; }

  for (int xc = 0; xc < 8; ++xc) {
    const int xb = xc * 32;
    float od[8], ob[8];
    *(float4*)&od[0] = *(const float4*)(orow + xb + x0);
    *(float4*)&od[4] = *(const float4*)(orow + xb + x0 + 4);
    *(float4*)&ob[0] = *(const float4*)(brow + xb + x0);
    *(float4*)&ob[4] = *(const float4*)(brow + xb + x0 + 4);
    bf16x8 pr, pi;
    #pragma unroll
    for (int j = 0; j < 8; ++j) {
      float s, c;
      __sincosf(w0 * od[j], &s, &c);
      pr[j] = f2bf(c * ob[j]);
      pi[j] = f2bf(s * ob[j]);
    }
    #pragma unroll
    for (int t = 0; t < 4; ++t) {
      const bf16x8 w_r  = *(const bf16x8*)(wrb + (size_t)t * 16 * 256 + xb);
      const bf16x8 w_i  = *(const bf16x8*)(wib + (size_t)t * 16 * 256 + xb);
      const bf16x8 nw_i = neg8(w_i);
      aR[t] = MFMA16(w_r,  pr, aR[t]);
      aR[t] = MFMA16(nw_i, pi, aR[t]);
      aI[t] = MFMA16(w_r,  pi, aI[t]);
      aI[t] = MFMA16(w_i,  pr, aI[t]);
    }
  }

  // D: col(lr) = y-local of this wave's slab (== y), row(lq*4+r) = kv-local
  #pragma unroll
  for (int t = 0; t < 4; ++t)
    #pragma unroll
    for (int r = 0; r < 4; ++r) {
      const int kv = t * 16 + lq * 4 + r;
      const size_t o = ((size_t)bb * 64 + kv) * 256 + y;
      Gr_t[o] = f2bf(aR[t][r]);
      Gi_t[o] = f2bf(aI[t][r]);
    }
}

// stage2: grid (4 uc, 8 bin, 16 b) = 512 blocks; barrier-free K-loop with
// manual register double-buffer; LDS only for transpose + S reduction.
__global__ __launch_bounds__(256, 4) void stage2(
    const short* __restrict__ Wr_t, const short* __restrict__ Wi_t,
    const short* __restrict__ Gr_t, const short* __restrict__ Gi_t,
    float* __restrict__ psf_raw, float* __restrict__ sums)
{
  const int tid = threadIdx.x;
  const int uc = blockIdx.x, bin = blockIdx.y, b = blockIdx.z;
  const int bb = b * N_BINS + bin;

  __shared__ float pvbuf[64 * 17];
  __shared__ float red[4];

  const int wave = tid >> 6, lane = tid & 63;
  const int lr = lane & 15, lq = lane >> 4;

  f32x4 hR = (f32x4)0.0f, hI = (f32x4)0.0f;

  const short* grb = Gr_t + ((size_t)bb * 64 + wave * 16 + lr) * 256 + lq * 8;
  const short* gib = Gi_t + ((size_t)bb * 64 + wave * 16 + lr) * 256 + lq * 8;
  const short* wrb = Wr_t + ((size_t)bin * 64 + uc * 16 + lr) * 256 + lq * 8;
  const short* wib = Wi_t + ((size_t)bin * 64 + uc * 16 + lr) * 256 + lq * 8;

  bf16x8 g_r = *(const bf16x8*)(grb);
  bf16x8 g_i = *(const bf16x8*)(gib);
  bf16x8 w_r = *(const bf16x8*)(wrb);
  bf16x8 w_i = *(const bf16x8*)(wib);

  for (int yc = 0; yc < 8; ++yc) {
    const bf16x8 cg_r = g_r, cg_i = g_i, cw_r = w_r, cw_i = w_i;
    if (yc < 7) {                       // prefetch next K-chunk
      const int yn = (yc + 1) * 32;
      g_r = *(const bf16x8*)(grb + yn);
      g_i = *(const bf16x8*)(gib + yn);
      w_r = *(const bf16x8*)(wrb + yn);
      w_i = *(const bf16x8*)(wib + yn);
    }
    const bf16x8 ng_i = neg8(cg_i);
    hR = MFMA16(cg_r, cw_r, hR);
    hR = MFMA16(ng_i, cw_i, hR);
    hI = MFMA16(cg_r, cw_i, hI);
    hI = MFMA16(cg_i, cw_r, hI);
  }

  float pv[4], lsum = 0.f;
  #pragma unroll
  for (int r = 0; r < 4; ++r) {
    pv[r] = hR[r] * hR[r] + hI[r] * hI[r];
    lsum += pv[r];
  }
  #pragma unroll
  for (int off = 32; off > 0; off >>= 1) lsum += __shfl_down(lsum, off);
  if (lane == 0) red[wave] = lsum;

  // transpose via LDS: D row(lq*4+r)=kv, col(lr)=ku_local
  #pragma unroll
  for (int r = 0; r < 4; ++r)
    pvbuf[(wave * 16 + lq * 4 + r) * 17 + lr] = pv[r];
  __syncthreads();

  if (tid == 0)
    sums[bb * 4 + uc] = red[0] + red[1] + red[2] + red[3];

  #pragma unroll
  for (int it = 0; it < 4; ++it) {
    const int i  = tid + it * 256;            // 0..1023
    const int ul = i >> 6;                    // 0..15
    const int v  = i & 63;
    psf_raw[(size_t)bb * 4096 + (uc * 16 + ul) * 64 + v] = pvbuf[v * 17 + ul];
  }
}

// combine: scale = sed[bin]/S(b,bin); out = sum_bin scale*pv. 256 blocks.
__global__ void combine(const float* __restrict__ psf_raw,
                        const float* __restrict__ sums,
                        const float* __restrict__ sed,
                        float* __restrict__ out) {
  __shared__ float sc[N_BINS];
  const int blk = blockIdx.x;
  const int b = blk >> 4;
  const int px = (blk & 15) * 256 + threadIdx.x;
  if (threadIdx.x < N_BINS) {
    const int bb = b * N_BINS + threadIdx.x;
    const float S = sums[bb * 4] + sums[bb * 4 + 1] + sums[bb * 4 + 2] + sums[bb * 4 + 3];
    sc[threadIdx.x] = sed[threadIdx.x] / S;
  }
  __syncthreads();
  float acc = 0.f;
  #pragma unroll
  for (int bin = 0; bin < N_BINS; ++bin)
    acc += sc[bin] * psf_raw[(size_t)(b * N_BINS + bin) * 4096 + px];
  out[b * 4096 + px] = acc;
}

extern "C" void kernel_launch(void* const* d_in, const int* in_sizes, int n_in,
                              void* d_out, int out_size, void* d_ws, size_t ws_size,
                              hipStream_t stream) {
  const float* opd     = (const float*)d_in[0];
  const float* obsc    = (const float*)d_in[1];
  const float* lambdas = (const float*)d_in[2];
  const float* sed     = (const float*)d_in[3];
  float* out = (float*)d_out;

  // ws: Wr_t 256KB | Wi_t 256KB | Gr_t 4MB | Gi_t 4MB | psf_raw 2MB | sums 2KB
  short* Wr_t = (short*)d_ws;
  short* Wi_t = Wr_t + (size_t)N_BINS * 64 * 256;
  short* Gr_t = Wi_t + (size_t)N_BINS * 64 * 256;
  short* Gi_t = Gr_t + (size_t)BATCH * N_BINS * 64 * 256;
  float* psf_raw = (float*)(Gi_t + (size_t)BATCH * N_BINS * 64 * 256);
  float* sums    = psf_raw + (size_t)BATCH * N_BINS * 4096;

  wprep<<<512, 256, 0, stream>>>(Wr_t, Wi_t);
  stage1<<<dim3(4, N_BINS, BATCH), 256, 0, stream>>>(opd, obsc, lambdas,
                                                     Wr_t, Wi_t, Gr_t, Gi_t);
  stage2<<<dim3(4, N_BINS, BATCH), 256, 0, stream>>>(Wr_t, Wi_t, Gr_t, Gi_t,
                                                     psf_raw, sums);
  combine<<<256, 256, 0, stream>>>(psf_raw, sums, sed, out);
}

// Round 10
// 95.744 us; speedup vs baseline: 1.7414x; 1.0668x over previous
//
#include <hip/hip_runtime.h>
#include <math.h>

#define PUPIL 256
#define N_BINS 8
#define BATCH 16

__constant__ int PHASE_NS_C[N_BINS] = {1024, 988, 952, 918, 886, 856, 828, 802};

typedef short bf16x8 __attribute__((ext_vector_type(8)));
typedef float f32x4  __attribute__((ext_vector_type(4)));
typedef int   i32x4  __attribute__((ext_vector_type(4)));

#define MFMA16(a, b, c) __builtin_amdgcn_mfma_f32_16x16x32_bf16((a), (b), (c), 0, 0, 0)

__device__ __forceinline__ short f2bf(float f) {   // RNE float->bf16
  unsigned u = __float_as_uint(f);
  u += 0x7FFFu + ((u >> 16) & 1u);
  return (short)(u >> 16);
}
__device__ __forceinline__ bf16x8 neg8(bf16x8 v) {
  i32x4 t = __builtin_bit_cast(i32x4, v);
  t ^= (int)0x80008000;
  return __builtin_bit_cast(bf16x8, t);
}

// ---------------------------------------------------------------------------
// PSF[u,v] = | sum_{y,x} P[y,x] W[y,u] W[x,v] |^2 ; W[n,k]=e^{-2pi i (k-32) n/N}
// R10 = R5's winning 3-node skeleton (wprep / fused / combine) with a LEAN
// fused kernel:
//  - stage1 barrier-free & P-LDS-free (R9-verified): wave = 16-row y-slab,
//    lane's B-frag = its own 8 sincos'd pixels; A-frags = W_t rows (L2-hot).
//    4 passes/wave cover 256 y; G^T[32kv][256y] lands in LDS only (33 KB).
//  - stage2 from LDS-G + global-W; |H|^2; per-half sum; transpose; store.
//  2 barriers total; ~42 KB LDS -> 3 blocks/CU (vs R5: 17 barriers, 1/CU).
// MFMA 16x16x32 bf16 (verified R4-R9): A[m=lane&15][k=quad*8+j] 16B contig,
// B-frag = B^T row, D: col(lane&15)=N-dim, row(quad*4+reg)=M-dim.
// ---------------------------------------------------------------------------

#define GP 258   // G LDS pitch (elements); stride 129 dw -> lr bank stride 1

// W_t[bin][k=64][n=256] bf16
__global__ void wprep(short* __restrict__ Wr_t, short* __restrict__ Wi_t) {
  int idx = blockIdx.x * 256 + threadIdx.x;   // 131072
  int n   = idx & 255;
  int k   = (idx >> 8) & 63;
  int bin = idx >> 14;
  int N = PHASE_NS_C[bin];
  int m = ((k - 32) * n) % N;
  if (m < 0) m += N;
  float ang = -6.283185307179586f * (float)m / (float)N;
  float s, c;
  __sincosf(ang, &s, &c);
  Wr_t[idx] = f2bf(c);
  Wi_t[idx] = f2bf(s);
}

// fused: grid (2 khalf, 8 bin, 16 b) = 256 blocks, 256 thr, ~42 KB LDS.
__global__ __launch_bounds__(256, 3) void fused(
    const float* __restrict__ opd, const float* __restrict__ obsc,
    const float* __restrict__ lambdas,
    const short* __restrict__ Wr_t, const short* __restrict__ Wi_t,
    float* __restrict__ psf_raw, float* __restrict__ sums)
{
  const int tid = threadIdx.x;
  const int khalf = blockIdx.x, bin = blockIdx.y, b = blockIdx.z;
  const int bb = b * N_BINS + bin;
  const float w0 = 6.283185307179586f / lambdas[bin];

  __shared__ short Gr[32 * GP], Gi[32 * GP];   // [kv_local][y] bf16
  __shared__ float pvbuf[64 * 33];             // [ku_local][kv_local]
  __shared__ float red[4];

  const int wave = tid >> 6, lane = tid & 63;
  const int lr = lane & 15, lq = lane >> 4;

  // ------------- stage 1: G^T[32 kv][256 y] into LDS, K = x -------------
  const short* wrb = Wr_t + ((size_t)bin * 64 + khalf * 32 + lr) * 256 + lq * 8;
  const short* wib = Wi_t + ((size_t)bin * 64 + khalf * 32 + lr) * 256 + lq * 8;

  for (int p = 0; p < 4; ++p) {
    const int slab = (wave * 4 + p) * 16;     // this pass's 16-row y-slab
    const int y = slab + lr;
    const float* orow = opd + ((size_t)b * PUPIL + y) * PUPIL;
    const float* brow = obsc + (size_t)y * PUPIL;

    f32x4 aR[2], aI[2];
    aR[0] = (f32x4)0.0f; aR[1] = (f32x4)0.0f;
    aI[0] = (f32x4)0.0f; aI[1] = (f32x4)0.0f;

    for (int xc = 0; xc < 8; ++xc) {
      const int xb = xc * 32;
      float od[8], ob[8];
      *(float4*)&od[0] = *(const float4*)(orow + xb + lq * 8);
      *(float4*)&od[4] = *(const float4*)(orow + xb + lq * 8 + 4);
      *(float4*)&ob[0] = *(const float4*)(brow + xb + lq * 8);
      *(float4*)&ob[4] = *(const float4*)(brow + xb + lq * 8 + 4);
      bf16x8 pr, pi;
      #pragma unroll
      for (int j = 0; j < 8; ++j) {
        float s, c;
        __sincosf(w0 * od[j], &s, &c);
        pr[j] = f2bf(c * ob[j]);
        pi[j] = f2bf(s * ob[j]);
      }
      #pragma unroll
      for (int t = 0; t < 2; ++t) {
        const bf16x8 w_r  = *(const bf16x8*)(wrb + (size_t)t * 16 * 256 + xb);
        const bf16x8 w_i  = *(const bf16x8*)(wib + (size_t)t * 16 * 256 + xb);
        const bf16x8 nw_i = neg8(w_i);
        aR[t] = MFMA16(w_r,  pr, aR[t]);
        aR[t] = MFMA16(nw_i, pi, aR[t]);
        aI[t] = MFMA16(w_r,  pi, aI[t]);
        aI[t] = MFMA16(w_i,  pr, aI[t]);
      }
    }
    // D: col(lr)=y-local (== this lane's y), row(lq*4+r)=kv-local
    #pragma unroll
    for (int t = 0; t < 2; ++t)
      #pragma unroll
      for (int r = 0; r < 4; ++r) {
        const int kvl = t * 16 + lq * 4 + r;
        Gr[kvl * GP + y] = f2bf(aR[t][r]);
        Gi[kvl * GP + y] = f2bf(aI[t][r]);
      }
  }
  __syncthreads();                             // G complete

  // ------------- stage 2: H^T[32 kv][64 ku], K = y -------------
  const short* w2rb = Wr_t + ((size_t)bin * 64 + wave * 16 + lr) * 256 + lq * 8;
  const short* w2ib = Wi_t + ((size_t)bin * 64 + wave * 16 + lr) * 256 + lq * 8;

  f32x4 hR[2], hI[2];
  hR[0] = (f32x4)0.0f; hR[1] = (f32x4)0.0f;
  hI[0] = (f32x4)0.0f; hI[1] = (f32x4)0.0f;

  for (int yc = 0; yc < 8; ++yc) {
    const int yb2 = yc * 32;
    const bf16x8 w_r = *(const bf16x8*)(w2rb + yb2);   // B-frag: n = ku
    const bf16x8 w_i = *(const bf16x8*)(w2ib + yb2);
    #pragma unroll
    for (int t = 0; t < 2; ++t) {
      const bf16x8 g_r  = *(const bf16x8*)&Gr[(t * 16 + lr) * GP + yb2 + lq * 8];
      const bf16x8 g_i  = *(const bf16x8*)&Gi[(t * 16 + lr) * GP + yb2 + lq * 8];
      const bf16x8 ng_i = neg8(g_i);
      hR[t] = MFMA16(g_r,  w_r, hR[t]);
      hR[t] = MFMA16(ng_i, w_i, hR[t]);
      hI[t] = MFMA16(g_r,  w_i, hI[t]);
      hI[t] = MFMA16(g_i,  w_r, hI[t]);
    }
  }

  // |H|^2 + partial S + transpose
  float pv[2][4], lsum = 0.f;
  #pragma unroll
  for (int t = 0; t < 2; ++t)
    #pragma unroll
    for (int r = 0; r < 4; ++r) {
      pv[t][r] = hR[t][r] * hR[t][r] + hI[t][r] * hI[t][r];
      lsum += pv[t][r];
    }
  #pragma unroll
  for (int off = 32; off > 0; off >>= 1) lsum += __shfl_down(lsum, off);
  if (lane == 0) red[wave] = lsum;

  const int u = wave * 16 + lr;                // D col -> ku
  #pragma unroll
  for (int t = 0; t < 2; ++t)
    #pragma unroll
    for (int r = 0; r < 4; ++r)
      pvbuf[u * 33 + t * 16 + lq * 4 + r] = pv[t][r];
  __syncthreads();

  if (tid == 0)
    sums[bb * 2 + khalf] = red[0] + red[1] + red[2] + red[3];

  #pragma unroll
  for (int k2 = 0; k2 < 8; ++k2) {
    const int i = tid + k2 * 256;              // 0..2047
    const int uu = i >> 5, vl = i & 31;
    psf_raw[(size_t)bb * 4096 + uu * 64 + khalf * 32 + vl] = pvbuf[uu * 33 + vl];
  }
}

// combine: scale = sed[bin]/(S0+S1); out = sum_bin scale*pv. 256 blocks.
__global__ void combine(const float* __restrict__ psf_raw,
                        const float* __restrict__ sums,
                        const float* __restrict__ sed,
                        float* __restrict__ out) {
  __shared__ float sc[N_BINS];
  const int blk = blockIdx.x;
  const int b = blk >> 4;
  const int px = (blk & 15) * 256 + threadIdx.x;
  if (threadIdx.x < N_BINS) {
    const int bb = b * N_BINS + threadIdx.x;
    sc[threadIdx.x] = sed[threadIdx.x] / (sums[bb * 2] + sums[bb * 2 + 1]);
  }
  __syncthreads();
  float acc = 0.f;
  #pragma unroll
  for (int bin = 0; bin < N_BINS; ++bin)
    acc += sc[bin] * psf_raw[(size_t)(b * N_BINS + bin) * 4096 + px];
  out[b * 4096 + px] = acc;
}

extern "C" void kernel_launch(void* const* d_in, const int* in_sizes, int n_in,
                              void* d_out, int out_size, void* d_ws, size_t ws_size,
                              hipStream_t stream) {
  const float* opd     = (const float*)d_in[0];
  const float* obsc    = (const float*)d_in[1];
  const float* lambdas = (const float*)d_in[2];
  const float* sed     = (const float*)d_in[3];
  float* out = (float*)d_out;

  // ws: Wr_t 256KB | Wi_t 256KB | psf_raw 2MB | sums 1KB
  short* Wr_t = (short*)d_ws;
  short* Wi_t = Wr_t + (size_t)N_BINS * 64 * 256;
  float* psf_raw = (float*)(Wi_t + (size_t)N_BINS * 64 * 256);
  float* sums    = psf_raw + (size_t)BATCH * N_BINS * 4096;

  wprep<<<512, 256, 0, stream>>>(Wr_t, Wi_t);
  fused<<<dim3(2, N_BINS, BATCH), 256, 0, stream>>>(opd, obsc, lambdas,
                                                    Wr_t, Wi_t, psf_raw, sums);
  combine<<<256, 256, 0, stream>>>(psf_raw, sums, sed, out);
}